// Round 13
// baseline (988.208 us; speedup 1.0000x reference)
//
#include <hip/hip_runtime.h>
#include <hip/hip_cooperative_groups.h>

namespace cg = cooperative_groups;

#define N_NODES 50000
#define E_EDGES 800000
#define IN_DIM  128
#define HIDDEN  96
#define NEG_SLOPE 0.2f
#define NCH ((N_NODES + 255) / 256)   // 196 chunks of 256 nodes

struct Params {
    const float* feats; const int* src; const int* dst;
    const float* W[3]; const float* al[3]; const float* ar[3]; const float* bb[3];
    float* A; float* B; float* el; float* er;
    int* degcur; int* off; int* bsum; int* ssrc;
    float* partial; float* out; int nblk;
};

// ---- GEMM + fused el/er (64 nodes/tile, 384 thr = 8 groups x 48 ch-pair) ----
template <int K>
__device__ __forceinline__ void gemm_phase(const float* __restrict__ h,
                                           const float* __restrict__ W,
                                           const float* __restrict__ al_g,
                                           const float* __restrict__ ar_g,
                                           float* __restrict__ feat,
                                           float* __restrict__ el,
                                           float* __restrict__ er,
                                           float* smem, int bid, int nblk) {
    const int tid = threadIdx.x;
    for (int t = bid; t * 64 < N_NODES; t += nblk) {
        int node0 = t * 64;
        int total4 = 64 * K / 4;
        for (int idx = tid; idx < total4; idx += 384) {
            int node = idx / (K / 4);
            int koff = (idx % (K / 4)) * 4;
            float4 v = make_float4(0.f, 0.f, 0.f, 0.f);
            if (node0 + node < N_NODES)
                v = *(const float4*)(&h[(size_t)(node0 + node) * K + koff]);
            *(float4*)(&smem[node * K + koff]) = v;
        }
        __syncthreads();
        int grp = tid / 48;
        int c = (tid % 48) * 2;
        int nb = grp * 8;
        float acc[8][2];
#pragma unroll
        for (int i = 0; i < 8; ++i) acc[i][0] = acc[i][1] = 0.f;
        for (int k = 0; k < K; k += 4) {
            float2 w0 = *(const float2*)&W[(k + 0) * 96 + c];
            float2 w1 = *(const float2*)&W[(k + 1) * 96 + c];
            float2 w2 = *(const float2*)&W[(k + 2) * 96 + c];
            float2 w3 = *(const float2*)&W[(k + 3) * 96 + c];
#pragma unroll
            for (int i = 0; i < 8; ++i) {
                float4 hv = *(const float4*)&smem[(nb + i) * K + k];
                acc[i][0] = fmaf(hv.x, w0.x, acc[i][0]);
                acc[i][1] = fmaf(hv.x, w0.y, acc[i][1]);
                acc[i][0] = fmaf(hv.y, w1.x, acc[i][0]);
                acc[i][1] = fmaf(hv.y, w1.y, acc[i][1]);
                acc[i][0] = fmaf(hv.z, w2.x, acc[i][0]);
                acc[i][1] = fmaf(hv.z, w2.y, acc[i][1]);
                acc[i][0] = fmaf(hv.w, w3.x, acc[i][0]);
                acc[i][1] = fmaf(hv.w, w3.y, acc[i][1]);
            }
        }
#pragma unroll
        for (int i = 0; i < 8; ++i) {
            int node = node0 + nb + i;
            if (node < N_NODES)
                *(float2*)&feat[(size_t)node * 96 + c] = make_float2(acc[i][0], acc[i][1]);
        }
        float alc0 = al_g[c], alc1 = al_g[c + 1];
        float arc0 = ar_g[c], arc1 = ar_g[c + 1];
        __syncthreads(); // all smem (h-tile) reads done; safe to reuse
        int base = tid * 17;
#pragma unroll
        for (int i = 0; i < 8; ++i) {
            smem[base + i * 2]     = acc[i][0] * alc0 + acc[i][1] * alc1;
            smem[base + i * 2 + 1] = acc[i][0] * arc0 + acc[i][1] * arc1;
        }
        __syncthreads();
        if (tid < 256) {
            int ig = tid >> 2;              // node in tile (0..63)
            int hh = tid & 3;               // head
            int g2 = ig >> 3, il = ig & 7;  // group, node-in-group
            float se = 0.f, sr = 0.f;
#pragma unroll
            for (int cc = 0; cc < 12; ++cc) {
                int tt = g2 * 48 + hh * 12 + cc;
                se += smem[tt * 17 + il * 2];
                sr += smem[tt * 17 + il * 2 + 1];
            }
            int node = node0 + ig;
            if (node < N_NODES) {
                el[node * 4 + hh] = se;
                er[node * 4 + hh] = sr;
            }
        }
        __syncthreads(); // partial reads done before next tile overwrites smem
    }
}

// ---- per-node softmax+aggregate, one wave per node (6 waves/block) ----
__device__ __forceinline__ void agg_phase(const int* __restrict__ off,
                                          const int* __restrict__ ssrc,
                                          const float* __restrict__ el,
                                          const float* __restrict__ er,
                                          const float* __restrict__ feat,
                                          const float* __restrict__ bias,
                                          float* __restrict__ out, int bid, int nblk) {
    const int tid = threadIdx.x;
    const int lane = tid & 63;
    const int wv = tid >> 6;          // 0..5
    const int j0 = lane >> 3;
    const int h = (lane >> 1) & 3;
    const int half = lane & 1;
    const int cbase = h * 24 + half * 12;
    const unsigned cboff = (unsigned)cbase * 4u;

    for (int base = bid * 6; base < N_NODES; base += nblk * 6) {
        int n = base + wv;
        if (n < N_NODES) {
            int start = off[n], deg = off[n + 1] - start;
            float er_h = er[(unsigned)n * 4u + h];

            float e_reg[4];
            unsigned s_reg[4];
            float lmax = -1e30f;
#pragma unroll
            for (int t = 0; t < 4; ++t) {
                int j = t * 8 + j0;
                bool act = (j < deg);
                unsigned s = act ? (unsigned)ssrc[start + j] : 0u;
                float e = -1e30f;
                if (act) {
                    e = el[s * 4u + h] + er_h;
                    e = (e > 0.f) ? e : NEG_SLOPE * e;
                }
                s_reg[t] = s;
                e_reg[t] = e;
                lmax = fmaxf(lmax, e);
            }
            for (int j = 32 + j0; j < deg; j += 8) {
                unsigned s = (unsigned)ssrc[start + j];
                float e = el[s * 4u + h] + er_h;
                e = (e > 0.f) ? e : NEG_SLOPE * e;
                lmax = fmaxf(lmax, e);
            }
            lmax = fmaxf(lmax, __shfl_xor(lmax, 8));
            lmax = fmaxf(lmax, __shfl_xor(lmax, 16));
            lmax = fmaxf(lmax, __shfl_xor(lmax, 32));
            float m = lmax;

            float acc[12];
#pragma unroll
            for (int c = 0; c < 12; ++c) acc[c] = 0.f;
            float den = 0.f;
#pragma unroll
            for (int t = 0; t < 4; ++t) {
                int j = t * 8 + j0;
                if (j < deg) {
                    float ex = __expf(e_reg[t] - m);
                    den += ex;
                    const float* fr = (const float*)((const char*)feat + (size_t)(s_reg[t] * 384u + cboff));
                    float4 v0 = *(const float4*)(fr + 0);
                    float4 v1 = *(const float4*)(fr + 4);
                    float4 v2 = *(const float4*)(fr + 8);
                    acc[0] = fmaf(ex, v0.x, acc[0]);   acc[1] = fmaf(ex, v0.y, acc[1]);
                    acc[2] = fmaf(ex, v0.z, acc[2]);   acc[3] = fmaf(ex, v0.w, acc[3]);
                    acc[4] = fmaf(ex, v1.x, acc[4]);   acc[5] = fmaf(ex, v1.y, acc[5]);
                    acc[6] = fmaf(ex, v1.z, acc[6]);   acc[7] = fmaf(ex, v1.w, acc[7]);
                    acc[8] = fmaf(ex, v2.x, acc[8]);   acc[9] = fmaf(ex, v2.y, acc[9]);
                    acc[10] = fmaf(ex, v2.z, acc[10]); acc[11] = fmaf(ex, v2.w, acc[11]);
                }
            }
            for (int j = 32 + j0; j < deg; j += 8) {
                unsigned s = (unsigned)ssrc[start + j];
                float e = el[s * 4u + h] + er_h;
                e = (e > 0.f) ? e : NEG_SLOPE * e;
                float ex = __expf(e - m);
                den += ex;
                const float* fr = (const float*)((const char*)feat + (size_t)(s * 384u + cboff));
                float4 v0 = *(const float4*)(fr + 0);
                float4 v1 = *(const float4*)(fr + 4);
                float4 v2 = *(const float4*)(fr + 8);
                acc[0] = fmaf(ex, v0.x, acc[0]);   acc[1] = fmaf(ex, v0.y, acc[1]);
                acc[2] = fmaf(ex, v0.z, acc[2]);   acc[3] = fmaf(ex, v0.w, acc[3]);
                acc[4] = fmaf(ex, v1.x, acc[4]);   acc[5] = fmaf(ex, v1.y, acc[5]);
                acc[6] = fmaf(ex, v1.z, acc[6]);   acc[7] = fmaf(ex, v1.w, acc[7]);
                acc[8] = fmaf(ex, v2.x, acc[8]);   acc[9] = fmaf(ex, v2.y, acc[9]);
                acc[10] = fmaf(ex, v2.z, acc[10]); acc[11] = fmaf(ex, v2.w, acc[11]);
            }

#pragma unroll
            for (int st = 8; st <= 32; st <<= 1) {
                den += __shfl_xor(den, st);
#pragma unroll
                for (int c = 0; c < 12; ++c) acc[c] += __shfl_xor(acc[c], st);
            }

            if (j0 == 0) {
                float rden = (den > 0.f) ? 1.f / den : 0.f;
                const float* bp = &bias[cbase];
                float o[12];
#pragma unroll
                for (int c = 0; c < 12; ++c) {
                    float v = acc[c] * rden + bp[c];
                    o[c] = (v > 0.f) ? v : (__expf(v) - 1.f);
                }
                float* op = &out[(size_t)n * 96 + cbase];
                *(float4*)(op + 0) = make_float4(o[0], o[1], o[2], o[3]);
                *(float4*)(op + 4) = make_float4(o[4], o[5], o[6], o[7]);
                *(float4*)(op + 8) = make_float4(o[8], o[9], o[10], o[11]);
            }
        }
    }
}

// ---- scan helpers (256-wide chunks processed by 384-thr blocks) ----
__device__ __forceinline__ void scan1_phase(const int* deg, int* bsum, int* ismem,
                                            int bid, int nblk) {
    const int tid = threadIdx.x;
    for (int b = bid; b < NCH; b += nblk) {
        int i = b * 256 + tid;
        int v = (tid < 256 && i < N_NODES) ? deg[i] : 0;
#pragma unroll
        for (int s = 1; s < 64; s <<= 1) v += __shfl_xor(v, s);
        if ((tid & 63) == 0) ismem[tid >> 6] = v;
        __syncthreads();
        if (tid == 0)
            bsum[b] = ismem[0] + ismem[1] + ismem[2] + ismem[3] + ismem[4] + ismem[5];
        __syncthreads();
    }
}

__device__ __forceinline__ void scan3_phase(const int* deg, const int* bsum,
                                            int* off, int* ismem, int bid, int nblk) {
    const int tid = threadIdx.x;
    const int lane = tid & 63, wv = tid >> 6;
    for (int b = bid; b < NCH; b += nblk) {
        int pv = (tid < b) ? bsum[tid] : 0;   // b <= 196 < 384
#pragma unroll
        for (int s = 1; s < 64; s <<= 1) pv += __shfl_xor(pv, s);
        int i = b * 256 + tid;
        int v = (tid < 256 && i < N_NODES) ? deg[i] : 0;
        int x = v;
#pragma unroll
        for (int s = 1; s < 64; s <<= 1) {
            int t2 = __shfl_up(x, s);
            if (lane >= s) x += t2;
        }
        if (lane == 63) ismem[wv] = x;
        if (lane == 0)  ismem[8 + wv] = pv;
        __syncthreads();
        int add = ismem[8] + ismem[9] + ismem[10] + ismem[11] + ismem[12] + ismem[13];
        for (int w = 0; w < wv; ++w) add += ismem[w];
        if (tid < 256 && i < N_NODES) off[i] = x - v + add;
        if (i == N_NODES - 1) off[N_NODES] = x + add;
        __syncthreads();
    }
}

// ---- the mega-kernel: entire 3-layer GAT forward in ONE dispatch ----
__global__ __launch_bounds__(384) void mega(Params P) {
    __shared__ float smem[8192]; // 32 KB: gemm h-tile (K=128) / elr staging / pool red
    int* ismem = (int*)smem;
    cg::grid_group grid = cg::this_grid();
    const int bid = blockIdx.x;
    const int nblk = P.nblk;
    const int tid = threadIdx.x;

    // P0: zero deg|cursor + layer-0 GEMM (independent of CSR)
    for (int i = bid * 384 + tid; i < N_NODES * 2; i += nblk * 384) P.degcur[i] = 0;
    gemm_phase<IN_DIM>(P.feats, P.W[0], P.al[0], P.ar[0], P.B, P.el, P.er, smem, bid, nblk);
    grid.sync();

    // P1: degree histogram
    for (int e = bid * 384 + tid; e < E_EDGES; e += nblk * 384)
        atomicAdd(&P.degcur[P.dst[e]], 1);
    grid.sync();

    // P2: chunk sums
    scan1_phase(P.degcur, P.bsum, ismem, bid, nblk);
    grid.sync();

    // P3: offsets
    scan3_phase(P.degcur, P.bsum, P.off, ismem, bid, nblk);
    grid.sync();

    // P4: CSR fill
    {
        int* cursor = P.degcur + N_NODES;
        for (int e = bid * 384 + tid; e < E_EDGES; e += nblk * 384) {
            int d = P.dst[e];
            int p = P.off[d] + atomicAdd(&cursor[d], 1);
            P.ssrc[p] = P.src[e];
        }
    }
    grid.sync();

    // P5..P9: agg0, gemm1, agg1, gemm2, agg2
    agg_phase(P.off, P.ssrc, P.el, P.er, P.B, P.bb[0], P.A, bid, nblk);
    grid.sync();
    gemm_phase<HIDDEN>(P.A, P.W[1], P.al[1], P.ar[1], P.B, P.el, P.er, smem, bid, nblk);
    grid.sync();
    agg_phase(P.off, P.ssrc, P.el, P.er, P.B, P.bb[1], P.A, bid, nblk);
    grid.sync();
    gemm_phase<HIDDEN>(P.A, P.W[2], P.al[2], P.ar[2], P.B, P.el, P.er, smem, bid, nblk);
    grid.sync();
    agg_phase(P.off, P.ssrc, P.el, P.er, P.B, P.bb[2], P.A, bid, nblk);
    grid.sync();

    // P10: pool stage 1 (per-block partials)
    {
        int r = tid / 96, c = tid % 96;
        float a = 0.f;
        for (int nr = bid * 4 + r; nr < N_NODES; nr += nblk * 4)
            a += P.A[(size_t)nr * 96 + c];
        __syncthreads();
        smem[tid] = a;
        __syncthreads();
        if (tid < 96)
            P.partial[bid * 96 + tid] =
                smem[tid] + smem[96 + tid] + smem[192 + tid] + smem[288 + tid];
    }
    grid.sync();

    // P11: pool stage 2 (block 0 reduces, writes out)
    if (bid == 0) {
        int g = tid / 96, c = tid % 96;
        float a = 0.f;
        for (int b = g; b < nblk; b += 4) a += P.partial[b * 96 + c];
        smem[tid] = a;
        __syncthreads();
        if (tid < 96)
            P.out[tid] = (smem[tid] + smem[96 + tid] + smem[192 + tid] + smem[288 + tid]) *
                         (1.0f / N_NODES);
    }
}

// ---------------- launch ----------------

extern "C" void kernel_launch(void* const* d_in, const int* in_sizes, int n_in,
                              void* d_out, int out_size, void* d_ws, size_t ws_size,
                              hipStream_t stream) {
    Params pr;
    pr.feats = (const float*)d_in[0];
    pr.src   = (const int*)d_in[1];
    pr.dst   = (const int*)d_in[2];
    for (int l = 0; l < 3; ++l) {
        pr.W[l]  = (const float*)d_in[3 + 4 * l];
        pr.al[l] = (const float*)d_in[4 + 4 * l];
        pr.ar[l] = (const float*)d_in[5 + 4 * l];
        pr.bb[l] = (const float*)d_in[6 + 4 * l];
    }

    char* p = (char*)d_ws;
    auto alloc = [&](size_t bytes) {
        void* r = (void*)p;
        p += (bytes + 255) & ~(size_t)255;
        return r;
    };
    pr.A       = (float*)alloc((size_t)N_NODES * 96 * 4);
    pr.B       = (float*)alloc((size_t)N_NODES * 96 * 4);
    pr.el      = (float*)alloc((size_t)N_NODES * 4 * 4);
    pr.er      = (float*)alloc((size_t)N_NODES * 4 * 4);
    pr.degcur  = (int*)alloc((size_t)N_NODES * 2 * 4);
    pr.off     = (int*)alloc((size_t)(N_NODES + 1) * 4);
    pr.bsum    = (int*)alloc((size_t)NCH * 4);
    pr.ssrc    = (int*)alloc((size_t)E_EDGES * 4);
    pr.partial = (float*)alloc((size_t)2048 * 96 * 4);
    pr.out     = (float*)d_out;

    int dev = 0;
    hipGetDevice(&dev);
    int nSM = 0;
    hipDeviceGetAttribute(&nSM, hipDeviceAttributeMultiprocessorCount, dev);
    if (nSM <= 0) nSM = 256;
    int maxB = 0;
    hipOccupancyMaxActiveBlocksPerMultiprocessor(&maxB, mega, 384, 0);
    if (maxB < 1) maxB = 1;
    int nblk = nSM * maxB;
    if (nblk > 2048) nblk = 2048; // partial-buffer cap
    pr.nblk = nblk;

    void* args[] = { &pr };
    hipLaunchCooperativeKernel((void*)mega, dim3(nblk), dim3(384), args, 0, stream);
}

// Round 15
// 420.472 us; speedup vs baseline: 2.3502x; 2.3502x over previous
//
#include <hip/hip_runtime.h>
#include <hip/hip_fp16.h>

#define N_NODES 50000
#define E_EDGES 800000
#define IN_DIM  128
#define HIDDEN  96
#define NEG_SLOPE 0.2f
#define POOL_BLOCKS 256

// ---------------- CSR build ----------------

// zero d_out folded in (block 0); deg histogram
__global__ void k_hist(const int* __restrict__ dst, int* __restrict__ deg,
                       float* __restrict__ out) {
    if (blockIdx.x == 0 && threadIdx.x < 96) out[threadIdx.x] = 0.f;
    int e = blockIdx.x * 256 + threadIdx.x;
    if (e < E_EDGES) atomicAdd(&deg[dst[e]], 1);
}

// single-kernel scan: each block self-computes its prefix from deg directly
__global__ __launch_bounds__(256) void k_scan(const int* __restrict__ deg,
                                              int* __restrict__ off, int n) {
    int tid = threadIdx.x;
    int lane = tid & 63, wv = tid >> 6;
    int base = blockIdx.x * 256;
    // prefix over all earlier chunks (coalesced grid-stride reduce)
    int pv = 0;
    for (int i = tid; i < base; i += 256) pv += deg[i];
#pragma unroll
    for (int s = 1; s < 64; s <<= 1) pv += __shfl_xor(pv, s);
    // local inclusive scan of this chunk
    int i = base + tid;
    int v = (i < n) ? deg[i] : 0;
    int x = v;
#pragma unroll
    for (int s = 1; s < 64; s <<= 1) {
        int t = __shfl_up(x, s);
        if (lane >= s) x += t;
    }
    __shared__ int wsum[4], psum[4];
    if (lane == 63) wsum[wv] = x;
    if (lane == 0)  psum[wv] = pv;
    __syncthreads();
    int add = psum[0] + psum[1] + psum[2] + psum[3];
    for (int w = 0; w < wv; ++w) add += wsum[w];
    if (i < n) off[i] = x - v + add;
    if (i == n - 1) off[n] = x + add;
}

__global__ void k_fill(const int* __restrict__ src, const int* __restrict__ dst,
                       const int* __restrict__ off, int* __restrict__ cursor,
                       int* __restrict__ ssrc) {
    int e = blockIdx.x * 256 + threadIdx.x;
    if (e < E_EDGES) {
        int d = dst[e];
        int p = off[d] + atomicAdd(&cursor[d], 1);
        ssrc[p] = src[e];
    }
}

// ---------------- per-layer kernels ----------------

// feat[N,96](fp16) = h[N,K] @ W[K,96] + fused el/er (fp32 from fp32 accs)
template <int K>
__global__ __launch_bounds__(384) void k_gemm(const float* __restrict__ h,
                                              const float* __restrict__ W,
                                              const float* __restrict__ al_g,
                                              const float* __restrict__ ar_g,
                                              __half* __restrict__ feat,
                                              float* __restrict__ el,
                                              float* __restrict__ er, int n) {
    constexpr int HL = 64 * K;
    constexpr int PT = 384 * 17;
    constexpr int SM = (HL > PT) ? HL : PT;
    __shared__ float smem[SM];
    float* hl = smem;

    int node0 = blockIdx.x * 64;
    int total4 = 64 * K / 4;
    for (int idx = threadIdx.x; idx < total4; idx += 384) {
        int node = idx / (K / 4);
        int koff = (idx % (K / 4)) * 4;
        float4 v = make_float4(0.f, 0.f, 0.f, 0.f);
        if (node0 + node < n)
            v = *(const float4*)(&h[(size_t)(node0 + node) * K + koff]);
        *(float4*)(&hl[node * K + koff]) = v;
    }
    __syncthreads();
    int grp = threadIdx.x / 48;        // 0..7
    int c = (threadIdx.x % 48) * 2;    // channel pair
    int nb = grp * 8;                  // 8 nodes per group
    float acc[8][2];
#pragma unroll
    for (int i = 0; i < 8; ++i) acc[i][0] = acc[i][1] = 0.f;
    for (int k = 0; k < K; k += 4) {
        float2 w0 = *(const float2*)&W[(k + 0) * 96 + c];
        float2 w1 = *(const float2*)&W[(k + 1) * 96 + c];
        float2 w2 = *(const float2*)&W[(k + 2) * 96 + c];
        float2 w3 = *(const float2*)&W[(k + 3) * 96 + c];
#pragma unroll
        for (int i = 0; i < 8; ++i) {
            float4 hv = *(const float4*)&hl[(nb + i) * K + k];
            acc[i][0] = fmaf(hv.x, w0.x, acc[i][0]);
            acc[i][1] = fmaf(hv.x, w0.y, acc[i][1]);
            acc[i][0] = fmaf(hv.y, w1.x, acc[i][0]);
            acc[i][1] = fmaf(hv.y, w1.y, acc[i][1]);
            acc[i][0] = fmaf(hv.z, w2.x, acc[i][0]);
            acc[i][1] = fmaf(hv.z, w2.y, acc[i][1]);
            acc[i][0] = fmaf(hv.w, w3.x, acc[i][0]);
            acc[i][1] = fmaf(hv.w, w3.y, acc[i][1]);
        }
    }
#pragma unroll
    for (int i = 0; i < 8; ++i) {
        int node = node0 + nb + i;
        if (node < n)
            *(__half2*)&feat[(size_t)node * 96 + c] =
                __floats2half2_rn(acc[i][0], acc[i][1]);
    }
    // el/er partials into reused LDS (pad 17 to spread banks)
    float alc0 = al_g[c], alc1 = al_g[c + 1];
    float arc0 = ar_g[c], arc1 = ar_g[c + 1];
    __syncthreads(); // all hl reads done; safe to reuse
    float* part = smem;
    int base = threadIdx.x * 17;
#pragma unroll
    for (int i = 0; i < 8; ++i) {
        part[base + i * 2]     = acc[i][0] * alc0 + acc[i][1] * alc1;
        part[base + i * 2 + 1] = acc[i][0] * arc0 + acc[i][1] * arc1;
    }
    __syncthreads();
    if (threadIdx.x < 256) {
        int ig = threadIdx.x >> 2;      // node in block (0..63)
        int hh = threadIdx.x & 3;       // head
        int g2 = ig >> 3, il = ig & 7;  // group, node-in-group
        float se = 0.f, sr = 0.f;
#pragma unroll
        for (int cc = 0; cc < 12; ++cc) {
            int t = g2 * 48 + hh * 12 + cc;
            se += part[t * 17 + il * 2];
            sr += part[t * 17 + il * 2 + 1];
        }
        int node = node0 + ig;
        if (node < n) {
            el[node * 4 + hh] = se;
            er[node * 4 + hh] = sr;
        }
    }
}

// per-node softmax + aggregation, one wave per node; fp16 feat gather
// lane = j0*8 + h*2 + half; channels [h*24 + half*12, +12)
__global__ __launch_bounds__(256) void k_agg(const int* __restrict__ off,
                                             const int* __restrict__ ssrc,
                                             const float* __restrict__ el,
                                             const float* __restrict__ er,
                                             const __half* __restrict__ feat,
                                             const float* __restrict__ bias,
                                             float* __restrict__ out) {
    int n = blockIdx.x * 4 + (threadIdx.x >> 6);
    if (n >= N_NODES) return;
    int lane = threadIdx.x & 63;
    int j0   = lane >> 3;        // 0..7
    int h    = (lane >> 1) & 3;  // head
    int half = lane & 1;         // half of head's 24 channels
    int cbase = h * 24 + half * 12;
    unsigned cboff = (unsigned)cbase * 2u;   // byte offset in fp16 row

    int start = off[n], deg = off[n + 1] - start;
    float er_h = er[(unsigned)n * 4u + h];

    // ---- pass A: gather e into regs (up to 32 edges), running max
    float e_reg[4];
    unsigned s_reg[4];
    float lmax = -1e30f;
#pragma unroll
    for (int t = 0; t < 4; ++t) {
        int j = t * 8 + j0;
        bool act = (j < deg);
        unsigned s = act ? (unsigned)ssrc[start + j] : 0u;
        float e = -1e30f;
        if (act) {
            e = el[s * 4u + h] + er_h;
            e = (e > 0.f) ? e : NEG_SLOPE * e;
        }
        s_reg[t] = s;
        e_reg[t] = e;
        lmax = fmaxf(lmax, e);
    }
    for (int j = 32 + j0; j < deg; j += 8) {
        unsigned s = (unsigned)ssrc[start + j];
        float e = el[s * 4u + h] + er_h;
        e = (e > 0.f) ? e : NEG_SLOPE * e;
        lmax = fmaxf(lmax, e);
    }
    lmax = fmaxf(lmax, __shfl_xor(lmax, 8));
    lmax = fmaxf(lmax, __shfl_xor(lmax, 16));
    lmax = fmaxf(lmax, __shfl_xor(lmax, 32));
    float m = lmax;

    // ---- pass B: fused exp + denom + 12-channel accumulate (fp16 gather)
    float acc[12];
#pragma unroll
    for (int c = 0; c < 12; ++c) acc[c] = 0.f;
    float den = 0.f;
#pragma unroll
    for (int t = 0; t < 4; ++t) {
        int j = t * 8 + j0;
        if (j < deg) {
            float ex = __expf(e_reg[t] - m);
            den += ex;
            const __half2* fr = (const __half2*)((const char*)feat +
                                  (size_t)(s_reg[t] * 192u + cboff));
            float2 f0 = __half22float2(fr[0]);
            float2 f1 = __half22float2(fr[1]);
            float2 f2 = __half22float2(fr[2]);
            float2 f3 = __half22float2(fr[3]);
            float2 f4 = __half22float2(fr[4]);
            float2 f5 = __half22float2(fr[5]);
            acc[0] = fmaf(ex, f0.x, acc[0]);   acc[1] = fmaf(ex, f0.y, acc[1]);
            acc[2] = fmaf(ex, f1.x, acc[2]);   acc[3] = fmaf(ex, f1.y, acc[3]);
            acc[4] = fmaf(ex, f2.x, acc[4]);   acc[5] = fmaf(ex, f2.y, acc[5]);
            acc[6] = fmaf(ex, f3.x, acc[6]);   acc[7] = fmaf(ex, f3.y, acc[7]);
            acc[8] = fmaf(ex, f4.x, acc[8]);   acc[9] = fmaf(ex, f4.y, acc[9]);
            acc[10] = fmaf(ex, f5.x, acc[10]); acc[11] = fmaf(ex, f5.y, acc[11]);
        }
    }
    for (int j = 32 + j0; j < deg; j += 8) {
        unsigned s = (unsigned)ssrc[start + j];
        float e = el[s * 4u + h] + er_h;
        e = (e > 0.f) ? e : NEG_SLOPE * e;
        float ex = __expf(e - m);
        den += ex;
        const __half2* fr = (const __half2*)((const char*)feat +
                              (size_t)(s * 192u + cboff));
        float2 f0 = __half22float2(fr[0]);
        float2 f1 = __half22float2(fr[1]);
        float2 f2 = __half22float2(fr[2]);
        float2 f3 = __half22float2(fr[3]);
        float2 f4 = __half22float2(fr[4]);
        float2 f5 = __half22float2(fr[5]);
        acc[0] = fmaf(ex, f0.x, acc[0]);   acc[1] = fmaf(ex, f0.y, acc[1]);
        acc[2] = fmaf(ex, f1.x, acc[2]);   acc[3] = fmaf(ex, f1.y, acc[3]);
        acc[4] = fmaf(ex, f2.x, acc[4]);   acc[5] = fmaf(ex, f2.y, acc[5]);
        acc[6] = fmaf(ex, f3.x, acc[6]);   acc[7] = fmaf(ex, f3.y, acc[7]);
        acc[8] = fmaf(ex, f4.x, acc[8]);   acc[9] = fmaf(ex, f4.y, acc[9]);
        acc[10] = fmaf(ex, f5.x, acc[10]); acc[11] = fmaf(ex, f5.y, acc[11]);
    }

    // ---- butterfly reduce over the 8 j-lanes (bits 3,4,5): 13 values
#pragma unroll
    for (int st = 8; st <= 32; st <<= 1) {
        den += __shfl_xor(den, st);
#pragma unroll
        for (int c = 0; c < 12; ++c) acc[c] += __shfl_xor(acc[c], st);
    }

    // ---- epilogue: lanes with j0==0 write their 12 channels
    if (j0 == 0) {
        float rden = (den > 0.f) ? 1.f / den : 0.f;
        const float* bp = &bias[cbase];
        float o[12];
#pragma unroll
        for (int c = 0; c < 12; ++c) {
            float v = acc[c] * rden + bp[c];
            o[c] = (v > 0.f) ? v : (__expf(v) - 1.f);
        }
        float* op = &out[(size_t)n * 96 + cbase];
        *(float4*)(op + 0) = make_float4(o[0], o[1], o[2], o[3]);
        *(float4*)(op + 4) = make_float4(o[4], o[5], o[6], o[7]);
        *(float4*)(op + 8) = make_float4(o[8], o[9], o[10], o[11]);
    }
}

// mean pool: block partials + one atomicAdd per channel per block
// (d_out zeroed by k_hist at the start of the launch)
__global__ __launch_bounds__(384) void k_pool(const float* __restrict__ h,
                                              float* __restrict__ out) {
    int r = threadIdx.x / 96;   // 0..3
    int c = threadIdx.x % 96;
    float a = 0.f;
    for (int nrow = blockIdx.x * 4 + r; nrow < N_NODES; nrow += POOL_BLOCKS * 4)
        a += h[(size_t)nrow * 96 + c];
    __shared__ float sred[4][96];
    sred[r][c] = a;
    __syncthreads();
    if (r == 0)
        atomicAdd(&out[c],
                  (sred[0][c] + sred[1][c] + sred[2][c] + sred[3][c]) * (1.0f / N_NODES));
}

// ---------------- launch ----------------

extern "C" void kernel_launch(void* const* d_in, const int* in_sizes, int n_in,
                              void* d_out, int out_size, void* d_ws, size_t ws_size,
                              hipStream_t stream) {
    const float* feats = (const float*)d_in[0];
    const int* src = (const int*)d_in[1];
    const int* dst = (const int*)d_in[2];

    char* p = (char*)d_ws;
    auto alloc = [&](size_t bytes) {
        void* r = (void*)p;
        p += (bytes + 255) & ~(size_t)255;
        return r;
    };
    float*  A      = (float*)alloc((size_t)N_NODES * 96 * 4);
    __half* B      = (__half*)alloc((size_t)N_NODES * 96 * 2);
    float*  el     = (float*)alloc((size_t)N_NODES * 4 * 4);
    float*  er     = (float*)alloc((size_t)N_NODES * 4 * 4);
    int* degcur    = (int*)alloc((size_t)N_NODES * 2 * 4); // deg | cursor
    int* off       = (int*)alloc((size_t)(N_NODES + 1) * 4);
    int* ssrc      = (int*)alloc((size_t)E_EDGES * 4);
    int* deg = degcur;
    int* cursor = degcur + N_NODES;

    hipMemsetAsync(degcur, 0, (size_t)N_NODES * 2 * 4, stream);

    const int NB = (N_NODES + 255) / 256;
    k_hist<<<(E_EDGES + 255) / 256, 256, 0, stream>>>(dst, deg, (float*)d_out);
    k_scan<<<NB, 256, 0, stream>>>(deg, off, N_NODES);
    k_fill<<<(E_EDGES + 255) / 256, 256, 0, stream>>>(src, dst, off, cursor, ssrc);

    const float* hin = feats;
    for (int l = 0; l < 3; ++l) {
        const float* W  = (const float*)d_in[3 + 4 * l];
        const float* al = (const float*)d_in[4 + 4 * l];
        const float* ar = (const float*)d_in[5 + 4 * l];
        const float* bb = (const float*)d_in[6 + 4 * l];

        if (l == 0)
            k_gemm<IN_DIM><<<(N_NODES + 63) / 64, 384, 0, stream>>>(hin, W, al, ar, B, el, er, N_NODES);
        else
            k_gemm<HIDDEN><<<(N_NODES + 63) / 64, 384, 0, stream>>>(hin, W, al, ar, B, el, er, N_NODES);

        k_agg<<<(N_NODES + 3) / 4, 256, 0, stream>>>(off, ssrc, el, er, B, bb, A);
        hin = A;
    }

    k_pool<<<POOL_BLOCKS, 384, 0, stream>>>(A, (float*)d_out);
}